// Round 19
// baseline (184.775 us; speedup 1.0000x reference)
//
#include <hip/hip_runtime.h>
#include <hip/hip_bf16.h>

#define B_ 8
#define S_ 4096
#define HID_ 640
#define KV_ 77
#define AU_ 16
#define CROSS_ 768
#define HEADS_ 10
#define DH_ 64
#define SCALE_ 0.125f

using f32x4 = __attribute__((ext_vector_type(4))) float;
using bf16x8 = __attribute__((ext_vector_type(8))) short;

__device__ __forceinline__ short bfc(float f) {
  __hip_bfloat16 h = __float2bfloat16(f);
  return __builtin_bit_cast(short, h);
}

__device__ __forceinline__ float bf2f(short s) {
  unsigned u = ((unsigned)(unsigned short)s) << 16;
  return __uint_as_float(u);
}

__device__ __forceinline__ void gload16(const void* g, void* lds) {
  __builtin_amdgcn_global_load_lds(
      (const __attribute__((address_space(1))) void*)g,
      (__attribute__((address_space(3))) void*)lds, 16, 0, 0);
}

__device__ __forceinline__ void cvt8(const float* src, short* dst) {
  const float4 a = *(const float4*)src;
  const float4 b = *(const float4*)(src + 4);
  bf16x8 v;
  v[0] = bfc(a.x); v[1] = bfc(a.y); v[2] = bfc(a.z); v[3] = bfc(a.w);
  v[4] = bfc(b.x); v[5] = bfc(b.y); v[6] = bfc(b.z); v[7] = bfc(b.w);
  *(bf16x8*)dst = v;
}

// ------------- prep: hs cvt + weight transpose + enc/au cvt (padded bf16)
__global__ __launch_bounds__(256) void prep_k(
    const float* hs, short* hsb, const float* enc, short* encb,
    const float* au, short* aub, const float* Wq, const float* Wk,
    const float* Wv, const float* Wauk, const float* Wauv, const float* Wout,
    short* Wqt, short* Wkt, short* Wvt, short* Waukt, short* Wauvt,
    short* Woutt) {
  __shared__ short Tl[64][72];
  const int t = threadIdx.x;
  int bid = blockIdx.x;
  if (bid < 10240) {
    int i = bid * 256 + t;
    cvt8(hs + (size_t)i * 8, hsb + (size_t)i * 8);
    return;
  }
  if (bid >= 10960) {
    if (bid < 11191) {
      int c = (bid - 10960) * 256 + t;
      cvt8(enc + (size_t)c * 8, encb + (size_t)c * 8);
    } else if (bid < 11248) {
      int j = (bid - 11191) * 256 + t;
      int4 z = {0, 0, 0, 0};
      *(int4*)(encb + (size_t)616 * 768 + (size_t)j * 8) = z;
    } else if (bid < 11296) {
      int c = (bid - 11248) * 256 + t;
      cvt8(au + (size_t)c * 8, aub + (size_t)c * 8);
    } else {
      int j = (bid - 11296) * 256 + t;
      int4 z = {0, 0, 0, 0};
      *(int4*)(aub + (size_t)128 * 768 + (size_t)j * 8) = z;
    }
    return;
  }
  int wb = bid - 10240;
  int z = wb / 120;
  int rem = wb - z * 120;
  int ky = rem / 10, nx = rem - ky * 10;
  const float* W;
  short* Wt;
  int K;
  switch (z) {
    case 0: W = Wq;   Wt = Wqt;   K = 640; break;
    case 1: W = Wk;   Wt = Wkt;   K = 768; break;
    case 2: W = Wv;   Wt = Wvt;   K = 768; break;
    case 3: W = Wauk; Wt = Waukt; K = 768; break;
    case 4: W = Wauv; Wt = Wauvt; K = 768; break;
    default: W = Wout; Wt = Woutt; K = 640; break;
  }
  int kt = ky * 64, nt = nx * 64;
  if (kt >= K) return;
#pragma unroll
  for (int j = 0; j < 16; ++j) {
    int i = t + j * 256;
    int r = i >> 6, c = i & 63;
    Tl[c][r] = bfc(W[(size_t)(kt + r) * 640 + nt + c]);
  }
  __syncthreads();
#pragma unroll
  for (int j = 0; j < 2; ++j) {
    int i = t + j * 256;
    int nl = i >> 3, c = i & 7;
    *(int4*)&Wt[(size_t)(nt + nl) * K + kt + c * 8] = *(int4*)&Tl[nl][c * 8];
  }
}

// ---------------------------------------------- big GEMM (R6 K-loop + R15
// LDS-bounce vectorized epilogue), templated on K (640 or 768).
template <int EPI, int KDIM>
__device__ __forceinline__ void gemm256(const short* Abf, const short* Bt,
                                        void* Cout, const float* bias,
                                        const void* resid, int N, int m0,
                                        int n0) {
  __shared__ short SH[24576];  // 48 KB: Al [256*64] | Bl [128*64]
  short* Al = SH;
  short* Bl = SH + 16384;
  const int t = threadIdx.x;
  const int lane = t & 63;
  const int wave = t >> 6;  // 0..7
  const int l15 = lane & 15, lg = lane >> 4;
  const int wr = (wave >> 1) * 64;
  const int wc = (wave & 1) * 64;

  f32x4 z4 = {0.f, 0.f, 0.f, 0.f};
  f32x4 acc[4][4];
#pragma unroll
  for (int i = 0; i < 4; ++i)
#pragma unroll
    for (int j = 0; j < 4; ++j) acc[i][j] = z4;

  for (int k0 = 0; k0 < KDIM; k0 += 64) {
#pragma unroll
    for (int i = 0; i < 4; ++i) {
      int chunk = wave * 256 + i * 64 + lane;
      int r = chunk >> 3, s = chunk & 7;
      gload16(Abf + (size_t)(m0 + r) * KDIM + k0 + ((s ^ (r & 7)) << 3),
              Al + (size_t)chunk * 8);
    }
#pragma unroll
    for (int i = 0; i < 2; ++i) {
      int chunk = wave * 128 + i * 64 + lane;
      int r = chunk >> 3, s = chunk & 7;
      gload16(Bt + (size_t)(n0 + r) * KDIM + k0 + ((s ^ (r & 7)) << 3),
              Bl + (size_t)chunk * 8);
    }
    __syncthreads();
#pragma unroll
    for (int ks = 0; ks < 2; ++ks) {
      bf16x8 af[4], bfr[4];
#pragma unroll
      for (int mi = 0; mi < 4; ++mi) {
        int row = wr + mi * 16 + l15;
        af[mi] = *(const bf16x8*)((const char*)(Al + row * 64) +
                                  ((ks * 64 + lg * 16) ^ ((row & 7) << 4)));
      }
#pragma unroll
      for (int ni = 0; ni < 4; ++ni) {
        int row = wc + ni * 16 + l15;
        bfr[ni] = *(const bf16x8*)((const char*)(Bl + row * 64) +
                                   ((ks * 64 + lg * 16) ^ ((row & 7) << 4)));
      }
#pragma unroll
      for (int mi = 0; mi < 4; ++mi)
#pragma unroll
        for (int ni = 0; ni < 4; ++ni)
          acc[mi][ni] = __builtin_amdgcn_mfma_f32_16x16x32_bf16(
              af[mi], bfr[ni], acc[mi][ni], 0, 0, 0);
    }
    __syncthreads();
  }

  // ---------------- epilogue (LDS bounce, vectorized global I/O)
  if (EPI == 0) {
    short* Cl = SH;  // bf16 [128][136]
#pragma unroll
    for (int half = 0; half < 2; ++half) {
      __syncthreads();
      if ((wave >> 2) == half) {
        int lwr = wr & 127;
#pragma unroll
        for (int mi = 0; mi < 4; ++mi)
#pragma unroll
          for (int ni = 0; ni < 4; ++ni)
#pragma unroll
            for (int j = 0; j < 4; ++j)
              Cl[(lwr + mi * 16 + lg * 4 + j) * 136 + wc + ni * 16 + l15] =
                  bfc(acc[mi][ni][j]);
      }
      __syncthreads();
#pragma unroll
      for (int p = 0; p < 4; ++p) {
        int idx = t + p * 512;
        int row = idx >> 4, cg = idx & 15;
        *(int4*)((short*)Cout + (size_t)(m0 + half * 128 + row) * N + n0 +
                 cg * 8) = *(const int4*)(Cl + row * 136 + cg * 8);
      }
    }
  } else {
    float* Clf = (float*)SH;  // f32 [64][132]
    float* biasl = (float*)((char*)SH + 40960);
    if (t < 32) *(float4*)(biasl + t * 4) = *(const float4*)(bias + n0 + t * 4);
#pragma unroll
    for (int q = 0; q < 4; ++q) {
      __syncthreads();
      if ((wave >> 1) == q) {
#pragma unroll
        for (int mi = 0; mi < 4; ++mi)
#pragma unroll
          for (int ni = 0; ni < 4; ++ni)
#pragma unroll
            for (int j = 0; j < 4; ++j)
              Clf[(mi * 16 + lg * 4 + j) * 132 + wc + ni * 16 + l15] =
                  acc[mi][ni][j];
      }
      __syncthreads();
#pragma unroll
      for (int p = 0; p < 4; ++p) {
        int idx = t + p * 512;
        int row = idx >> 5, f4 = idx & 31;
        size_t grow = (size_t)(m0 + q * 64 + row);
        int gcol = n0 + f4 * 4;
        float4 v = *(const float4*)(Clf + row * 132 + f4 * 4);
        float4 bv = *(const float4*)(biasl + f4 * 4);
        if (EPI == 2) {
          short4 rs = *(const short4*)((const short*)resid + grow * N + gcol);
          v.x += bv.x + bf2f(rs.x);
          v.y += bv.y + bf2f(rs.y);
          v.z += bv.z + bf2f(rs.z);
          v.w += bv.w + bf2f(rs.w);
        } else {
          float4 rf = *(const float4*)((const float*)resid + grow * N + gcol);
          v.x += bv.x + rf.x;
          v.y += bv.y + rf.y;
          v.z += bv.z + rf.z;
          v.w += bv.w + rf.w;
        }
        *(float4*)((float*)Cout + grow * N + gcol) = v;
      }
    }
  }
}

// XCD-chunked swizzle for the 640-block big-GEMM grids (640 = 8 x 80, exact).
__device__ __forceinline__ void xcd_swz(int& mt, int& nt) {
  int flat = blockIdx.y * 128 + blockIdx.x;
  int swz = (flat & 7) * 80 + (flat >> 3);
  mt = swz & 127;
  nt = swz >> 7;
}

__global__ __launch_bounds__(512, 4) void gemm_q_k(const short* A,
                                                   const short* Bt, short* C) {
  int mt, nt;
  xcd_swz(mt, nt);
  gemm256<0, 640>(A, Bt, C, nullptr, nullptr, HID_, mt * 256, nt * 128);
}

__global__ __launch_bounds__(512, 4) void gemm_out_f32r(const short* A,
                                                        const short* Bt,
                                                        float* C,
                                                        const float* bias,
                                                        const float* resid) {
  int mt, nt;
  xcd_swz(mt, nt);
  gemm256<1, 640>(A, Bt, C, bias, resid, HID_, mt * 256, nt * 128);
}

__global__ __launch_bounds__(512, 4) void gemm_out_b16r(const short* A,
                                                        const short* Bt,
                                                        float* C,
                                                        const float* bias,
                                                        const short* resid) {
  int mt, nt;
  xcd_swz(mt, nt);
  gemm256<2, 640>(A, Bt, C, bias, resid, HID_, mt * 256, nt * 128);
}

// proj4 as full gemm256 over padded bf16 A (encb 768 rows / aub 256 rows).
__global__ __launch_bounds__(512, 4) void proj4_k(const short* encb,
                                                  const short* aub,
                                                  const short* Wkt,
                                                  const short* Wvt,
                                                  const short* Waukt,
                                                  const short* Wauvt,
                                                  short* Kb, short* Vb,
                                                  short* AKb, short* AVb) {
  int z = blockIdx.z;
  if (z >= 2 && blockIdx.x > 0) return;
  const short* A = (z < 2) ? encb : aub;
  const short* Bt = (z == 0) ? Wkt : (z == 1) ? Wvt : (z == 2) ? Waukt : Wauvt;
  short* O = (z == 0) ? Kb : (z == 1) ? Vb : (z == 2) ? AKb : AVb;
  gemm256<0, 768>(A, Bt, O, nullptr, nullptr, HID_, blockIdx.x * 256,
                  blockIdx.y * 128);
}

// ---------------------------------------------------------------- attention
// R17 structure (best measured): Qt via gload16 + per-wave vmcnt(0); AU folded
// into PV (AUV -> Vt cols 80..95, g-prescaled mask -> Pl cols 80..95); no-max
// softmax (scores O(5); masked cols exp(-1e30)=+0); LDS 47.5 KB -> 3
// blocks/CU; zero barriers in the q-loop; Ob may alias Qb (race-free).
__global__ __launch_bounds__(256) void attn_k(const short* Qb, const short* Kb,
                                              const short* Vb, const short* AKb,
                                              const short* AVb, short* Ob,
                                              const float* temp,
                                              const float* gate) {
  __shared__ short Qt[64 * 64];   // 8 KB, linear+swizzled (gload16 dest)
  __shared__ short Kl[80][72];    // 11.25 KB (rows 77..79 garbage, masked)
  __shared__ short Vt[64][104];   // 13 KB: V^T kv 0..76 | 0 | AUV^T 80..95
  __shared__ short Pl[64][104];   // 13 KB: P 0..79 | g*mask 80..95
  __shared__ short AUKl[16][72];  // 2.25 KB

  const int t = threadIdx.x;
  const int lane = t & 63, wave = t >> 6;
  const int l15 = lane & 15, lg = lane >> 4;
  const int qbase = blockIdx.x * 512;
  const int h = blockIdx.y;
  const int b = blockIdx.z;
  const int rw = wave * 16;
  f32x4 z4 = {0.f, 0.f, 0.f, 0.f};

  for (int i = t; i < 64 * 3; i += 256) {
    int r = i / 3, c = i - r * 3;
    Vt[r][77 + c] = 0;
  }
#pragma unroll
  for (int j = 0; j < 3; ++j) {
    int i = t + j * 256;
    if (i < KV_ * 8) {
      int r = i >> 3, c8 = i & 7;
      *(int4*)&Kl[r][c8 * 8] =
          *(const int4*)(Kb + (size_t)(b * KV_ + r) * HID_ + h * DH_ + c8 * 8);
    }
  }
  for (int i = t; i < KV_ * DH_; i += 256) {
    int d = i & 63, kv = i >> 6;
    Vt[d][kv] = Vb[(size_t)(b * KV_ + kv) * HID_ + h * DH_ + d];
  }
  if (t < AU_ * 8) {
    int r = t >> 3, c8 = t & 7;
    *(int4*)&AUKl[r][c8 * 8] =
        *(const int4*)(AKb + (size_t)(b * AU_ + r) * HID_ + h * DH_ + c8 * 8);
  }
  for (int i = t; i < AU_ * DH_; i += 256) {
    int d = i & 63, a = i >> 6;
    Vt[d][80 + a] = AVb[(size_t)(b * AU_ + a) * HID_ + h * DH_ + d];
  }
  __syncthreads();  // the ONLY block-wide barrier

  const float invT = 1.f / (fabsf(temp[0]) + 1e-6f);
  const float g = gate[0];  // AU_SCALE = 1

  for (int qi = 0; qi < 8; ++qi) {
    const int q0 = qbase + qi * 64;
#pragma unroll
    for (int i2 = 0; i2 < 2; ++i2) {
      int chunk = wave * 128 + i2 * 64 + lane;
      int r = chunk >> 3, s = chunk & 7;
      const short* src = Qb + (size_t)(b * S_ + q0 + r) * HID_ + h * DH_ +
                         ((s ^ (r & 7)) << 3);
      gload16(src, Qt + (wave * 128 + i2 * 64) * 8);
    }
    asm volatile("s_waitcnt vmcnt(0)" ::: "memory");

    f32x4 accS[5], accA = z4;
#pragma unroll
    for (int c = 0; c < 5; ++c) accS[c] = z4;
#pragma unroll
    for (int ks = 0; ks < 2; ++ks) {
      const char* qrow = (const char*)(Qt + (rw + l15) * 64);
      bf16x8 aq =
          *(const bf16x8*)(qrow + ((ks * 64 + lg * 16) ^ ((l15 & 7) << 4)));
#pragma unroll
      for (int c = 0; c < 5; ++c) {
        bf16x8 bk = *(const bf16x8*)&Kl[c * 16 + l15][ks * 32 + lg * 8];
        accS[c] =
            __builtin_amdgcn_mfma_f32_16x16x32_bf16(aq, bk, accS[c], 0, 0, 0);
      }
      bf16x8 ba = *(const bf16x8*)&AUKl[l15][ks * 32 + lg * 8];
      accA = __builtin_amdgcn_mfma_f32_16x16x32_bf16(aq, ba, accA, 0, 0, 0);
    }

    // softmax WITHOUT max-subtraction (scores O(5); masked -> exp(-1e30)=0)
#pragma unroll
    for (int j = 0; j < 4; ++j) {
      float p[5];
      float s = 0.f;
#pragma unroll
      for (int c = 0; c < 5; ++c) {
        int col = c * 16 + l15;
        float vv = (col < KV_) ? accS[c][j] * SCALE_ : -1e30f;
        p[c] = __expf(vv);
        s += p[c];
      }
#pragma unroll
      for (int off = 1; off < 16; off <<= 1) s += __shfl_xor(s, off);
      float inv = 1.f / s;
      int r = rw + lg * 4 + j;
#pragma unroll
      for (int c = 0; c < 5; ++c) Pl[r][c * 16 + l15] = bfc(p[c] * inv);
      int gi = q0 + r;
      float lx = -1.f + 2.f * (float)(gi & 63) / 63.f;
      float ly = -1.f + 2.f * (float)(gi >> 6 & 63) / 63.f;
      float pr = __expf(-(lx * lx + ly * ly) * (1.0f / 0.605f));
      float as = accA[j] * SCALE_ * invT;
      float sg = 1.f / (1.f + __expf(-as));
      Pl[r][80 + l15] = bfc((sg * pr * 0.9f + 0.1f) * g);
    }
    // no barrier: PV reads only this wave's own Pl rows

    f32x4 accO[4];
#pragma unroll
    for (int c = 0; c < 4; ++c) accO[c] = z4;
#pragma unroll
    for (int kk = 0; kk < 96; kk += 32) {
      bf16x8 ap = *(const bf16x8*)&Pl[rw + l15][kk + lg * 8];
#pragma unroll
      for (int c = 0; c < 4; ++c) {
        bf16x8 bv = *(const bf16x8*)&Vt[c * 16 + l15][kk + lg * 8];
        accO[c] =
            __builtin_amdgcn_mfma_f32_16x16x32_bf16(ap, bv, accO[c], 0, 0, 0);
      }
    }
#pragma unroll
    for (int c = 0; c < 4; ++c)
#pragma unroll
      for (int j = 0; j < 4; ++j) {
        int r = rw + lg * 4 + j;
        Pl[r][c * 16 + l15] = bfc(accO[c][j]);
      }
#pragma unroll
    for (int i2 = 0; i2 < 2; ++i2) {
      int idx = lane + i2 * 64;
      int r = rw + (idx >> 3), cg = idx & 7;
      *(int4*)(Ob + (size_t)(b * S_ + q0 + r) * HID_ + h * DH_ + cg * 8) =
          *(const int4*)&Pl[r][cg * 8];
    }
  }
}

// ---------------------------------------------------------------- launcher
extern "C" void kernel_launch(void* const* d_in, const int* in_sizes, int n_in,
                              void* d_out, int out_size, void* d_ws,
                              size_t ws_size, hipStream_t stream) {
  const float* hs = (const float*)d_in[0];
  const float* enc = (const float*)d_in[1];
  const float* au = (const float*)d_in[2];
  const float* Wq = (const float*)d_in[3];
  const float* Wk = (const float*)d_in[4];
  const float* Wv = (const float*)d_in[5];
  const float* Wauk = (const float*)d_in[6];
  const float* Wauv = (const float*)d_in[7];
  const float* Wout = (const float*)d_in[8];
  const float* bout = (const float*)d_in[9];
  const float* temp = (const float*)d_in[10];
  const float* gate = (const float*)d_in[11];
  float* out = (float*)d_out;
  char* ws = (char*)d_ws;

  const size_t szKpad = (size_t)768 * HID_ * 2;
  const size_t szAUpad = (size_t)256 * HID_ * 2;
  const size_t szW640 = (size_t)HID_ * HID_ * 2;
  const size_t szW768 = (size_t)HID_ * CROSS_ * 2;
  const size_t szENC = (size_t)768 * CROSS_ * 2;
  const size_t szAUB = (size_t)256 * CROSS_ * 2;
  const size_t szHS = (size_t)B_ * S_ * HID_ * 2;

  size_t off = 0;
  short* Kbf = (short*)(ws + off);    off += szKpad;
  short* Vbf = (short*)(ws + off);    off += szKpad;
  short* AUKbf = (short*)(ws + off);  off += szAUpad;
  short* AUVbf = (short*)(ws + off);  off += szAUpad;
  short* Wqt = (short*)(ws + off);    off += szW640;
  short* Wkt = (short*)(ws + off);    off += szW768;
  short* Wvt = (short*)(ws + off);    off += szW768;
  short* Waukt = (short*)(ws + off);  off += szW768;
  short* Wauvt = (short*)(ws + off);  off += szW768;
  short* Woutt = (short*)(ws + off);  off += szW640;
  short* encb = (short*)(ws + off);   off += szENC;
  short* aub = (short*)(ws + off);    off += szAUB;
  short* Qbf = (short*)(ws + off);    off += szHS;
  short* Abf = Qbf;                   // ALIAS: attn overwrites Q in place

  bool hsb_in_ws = (ws_size >= off + szHS);
  short* hsb = hsb_in_ws ? (short*)(ws + off) : (short*)d_out;

  prep_k<<<11344, 256, 0, stream>>>(hs, hsb, enc, encb, au, aub, Wq, Wk, Wv,
                                    Wauk, Wauv, Wout, Wqt, Wkt, Wvt, Waukt,
                                    Wauvt, Woutt);
  proj4_k<<<dim3(3, 5, 4), 512, 0, stream>>>(encb, aub, Wkt, Wvt, Waukt,
                                             Wauvt, Kbf, Vbf, AUKbf, AUVbf);
  gemm_q_k<<<dim3(128, 5), 512, 0, stream>>>(hsb, Wqt, Qbf);
  attn_k<<<dim3(8, HEADS_, B_), 256, 0, stream>>>(Qbf, Kbf, Vbf, AUKbf, AUVbf,
                                                  Abf, temp, gate);
  if (hsb_in_ws) {
    gemm_out_b16r<<<dim3(128, 5), 512, 0, stream>>>(Abf, Woutt, out, bout,
                                                    hsb);
  } else {
    gemm_out_f32r<<<dim3(128, 5), 512, 0, stream>>>(Abf, Woutt, out, bout,
                                                    hs);
  }
}

// Round 20
// 174.395 us; speedup vs baseline: 1.0595x; 1.0595x over previous
//
#include <hip/hip_runtime.h>
#include <hip/hip_bf16.h>

#define B_ 8
#define S_ 4096
#define HID_ 640
#define KV_ 77
#define AU_ 16
#define CROSS_ 768
#define HEADS_ 10
#define DH_ 64
#define SCALE_ 0.125f

using f32x4 = __attribute__((ext_vector_type(4))) float;
using bf16x8 = __attribute__((ext_vector_type(8))) short;

__device__ __forceinline__ short bfc(float f) {
  __hip_bfloat16 h = __float2bfloat16(f);
  return __builtin_bit_cast(short, h);
}

__device__ __forceinline__ float bf2f(short s) {
  unsigned u = ((unsigned)(unsigned short)s) << 16;
  return __uint_as_float(u);
}

__device__ __forceinline__ void gload16(const void* g, void* lds) {
  __builtin_amdgcn_global_load_lds(
      (const __attribute__((address_space(1))) void*)g,
      (__attribute__((address_space(3))) void*)lds, 16, 0, 0);
}

__device__ __forceinline__ void cvt8(const float* src, short* dst) {
  const float4 a = *(const float4*)src;
  const float4 b = *(const float4*)(src + 4);
  bf16x8 v;
  v[0] = bfc(a.x); v[1] = bfc(a.y); v[2] = bfc(a.z); v[3] = bfc(a.w);
  v[4] = bfc(b.x); v[5] = bfc(b.y); v[6] = bfc(b.z); v[7] = bfc(b.w);
  *(bf16x8*)dst = v;
}

// ------------- prep: hs cvt + weight transpose + enc/au cvt (padded bf16)
__global__ __launch_bounds__(256) void prep_k(
    const float* hs, short* hsb, const float* enc, short* encb,
    const float* au, short* aub, const float* Wq, const float* Wk,
    const float* Wv, const float* Wauk, const float* Wauv, const float* Wout,
    short* Wqt, short* Wkt, short* Wvt, short* Waukt, short* Wauvt,
    short* Woutt) {
  __shared__ short Tl[64][72];
  const int t = threadIdx.x;
  int bid = blockIdx.x;
  if (bid < 10240) {
    int i = bid * 256 + t;
    cvt8(hs + (size_t)i * 8, hsb + (size_t)i * 8);
    return;
  }
  if (bid >= 10960) {
    if (bid < 11191) {
      int c = (bid - 10960) * 256 + t;
      cvt8(enc + (size_t)c * 8, encb + (size_t)c * 8);
    } else if (bid < 11248) {
      int j = (bid - 11191) * 256 + t;
      int4 z = {0, 0, 0, 0};
      *(int4*)(encb + (size_t)616 * 768 + (size_t)j * 8) = z;
    } else if (bid < 11296) {
      int c = (bid - 11248) * 256 + t;
      cvt8(au + (size_t)c * 8, aub + (size_t)c * 8);
    } else {
      int j = (bid - 11296) * 256 + t;
      int4 z = {0, 0, 0, 0};
      *(int4*)(aub + (size_t)128 * 768 + (size_t)j * 8) = z;
    }
    return;
  }
  int wb = bid - 10240;
  int z = wb / 120;
  int rem = wb - z * 120;
  int ky = rem / 10, nx = rem - ky * 10;
  const float* W;
  short* Wt;
  int K;
  switch (z) {
    case 0: W = Wq;   Wt = Wqt;   K = 640; break;
    case 1: W = Wk;   Wt = Wkt;   K = 768; break;
    case 2: W = Wv;   Wt = Wvt;   K = 768; break;
    case 3: W = Wauk; Wt = Waukt; K = 768; break;
    case 4: W = Wauv; Wt = Wauvt; K = 768; break;
    default: W = Wout; Wt = Woutt; K = 640; break;
  }
  int kt = ky * 64, nt = nx * 64;
  if (kt >= K) return;
#pragma unroll
  for (int j = 0; j < 16; ++j) {
    int i = t + j * 256;
    int r = i >> 6, c = i & 63;
    Tl[c][r] = bfc(W[(size_t)(kt + r) * 640 + nt + c]);
  }
  __syncthreads();
#pragma unroll
  for (int j = 0; j < 2; ++j) {
    int i = t + j * 256;
    int nl = i >> 3, c = i & 7;
    *(int4*)&Wt[(size_t)(nt + nl) * K + kt + c * 8] = *(int4*)&Tl[nl][c * 8];
  }
}

// ---------------------------------------------- big GEMM (R6 K-loop + R15
// LDS-bounce vectorized epilogue), templated on K (640 or 768).
template <int EPI, int KDIM>
__device__ __forceinline__ void gemm256(const short* Abf, const short* Bt,
                                        void* Cout, const float* bias,
                                        const void* resid, int N, int m0,
                                        int n0) {
  __shared__ short SH[24576];  // 48 KB: Al [256*64] | Bl [128*64]
  short* Al = SH;
  short* Bl = SH + 16384;
  const int t = threadIdx.x;
  const int lane = t & 63;
  const int wave = t >> 6;  // 0..7
  const int l15 = lane & 15, lg = lane >> 4;
  const int wr = (wave >> 1) * 64;
  const int wc = (wave & 1) * 64;

  f32x4 z4 = {0.f, 0.f, 0.f, 0.f};
  f32x4 acc[4][4];
#pragma unroll
  for (int i = 0; i < 4; ++i)
#pragma unroll
    for (int j = 0; j < 4; ++j) acc[i][j] = z4;

  for (int k0 = 0; k0 < KDIM; k0 += 64) {
#pragma unroll
    for (int i = 0; i < 4; ++i) {
      int chunk = wave * 256 + i * 64 + lane;
      int r = chunk >> 3, s = chunk & 7;
      gload16(Abf + (size_t)(m0 + r) * KDIM + k0 + ((s ^ (r & 7)) << 3),
              Al + (size_t)chunk * 8);
    }
#pragma unroll
    for (int i = 0; i < 2; ++i) {
      int chunk = wave * 128 + i * 64 + lane;
      int r = chunk >> 3, s = chunk & 7;
      gload16(Bt + (size_t)(n0 + r) * KDIM + k0 + ((s ^ (r & 7)) << 3),
              Bl + (size_t)chunk * 8);
    }
    __syncthreads();
#pragma unroll
    for (int ks = 0; ks < 2; ++ks) {
      bf16x8 af[4], bfr[4];
#pragma unroll
      for (int mi = 0; mi < 4; ++mi) {
        int row = wr + mi * 16 + l15;
        af[mi] = *(const bf16x8*)((const char*)(Al + row * 64) +
                                  ((ks * 64 + lg * 16) ^ ((row & 7) << 4)));
      }
#pragma unroll
      for (int ni = 0; ni < 4; ++ni) {
        int row = wc + ni * 16 + l15;
        bfr[ni] = *(const bf16x8*)((const char*)(Bl + row * 64) +
                                   ((ks * 64 + lg * 16) ^ ((row & 7) << 4)));
      }
#pragma unroll
      for (int mi = 0; mi < 4; ++mi)
#pragma unroll
        for (int ni = 0; ni < 4; ++ni)
          acc[mi][ni] = __builtin_amdgcn_mfma_f32_16x16x32_bf16(
              af[mi], bfr[ni], acc[mi][ni], 0, 0, 0);
    }
    __syncthreads();
  }

  // ---------------- epilogue (LDS bounce, vectorized global I/O)
  if (EPI == 0) {
    short* Cl = SH;  // bf16 [128][136]
#pragma unroll
    for (int half = 0; half < 2; ++half) {
      __syncthreads();
      if ((wave >> 2) == half) {
        int lwr = wr & 127;
#pragma unroll
        for (int mi = 0; mi < 4; ++mi)
#pragma unroll
          for (int ni = 0; ni < 4; ++ni)
#pragma unroll
            for (int j = 0; j < 4; ++j)
              Cl[(lwr + mi * 16 + lg * 4 + j) * 136 + wc + ni * 16 + l15] =
                  bfc(acc[mi][ni][j]);
      }
      __syncthreads();
#pragma unroll
      for (int p = 0; p < 4; ++p) {
        int idx = t + p * 512;
        int row = idx >> 4, cg = idx & 15;
        *(int4*)((short*)Cout + (size_t)(m0 + half * 128 + row) * N + n0 +
                 cg * 8) = *(const int4*)(Cl + row * 136 + cg * 8);
      }
    }
  } else {
    float* Clf = (float*)SH;  // f32 [64][132]
    float* biasl = (float*)((char*)SH + 40960);
    if (t < 32) *(float4*)(biasl + t * 4) = *(const float4*)(bias + n0 + t * 4);
#pragma unroll
    for (int q = 0; q < 4; ++q) {
      __syncthreads();
      if ((wave >> 1) == q) {
#pragma unroll
        for (int mi = 0; mi < 4; ++mi)
#pragma unroll
          for (int ni = 0; ni < 4; ++ni)
#pragma unroll
            for (int j = 0; j < 4; ++j)
              Clf[(mi * 16 + lg * 4 + j) * 132 + wc + ni * 16 + l15] =
                  acc[mi][ni][j];
      }
      __syncthreads();
#pragma unroll
      for (int p = 0; p < 4; ++p) {
        int idx = t + p * 512;
        int row = idx >> 5, f4 = idx & 31;
        size_t grow = (size_t)(m0 + q * 64 + row);
        int gcol = n0 + f4 * 4;
        float4 v = *(const float4*)(Clf + row * 132 + f4 * 4);
        float4 bv = *(const float4*)(biasl + f4 * 4);
        if (EPI == 2) {
          short4 rs = *(const short4*)((const short*)resid + grow * N + gcol);
          v.x += bv.x + bf2f(rs.x);
          v.y += bv.y + bf2f(rs.y);
          v.z += bv.z + bf2f(rs.z);
          v.w += bv.w + bf2f(rs.w);
        } else {
          float4 rf = *(const float4*)((const float*)resid + grow * N + gcol);
          v.x += bv.x + rf.x;
          v.y += bv.y + rf.y;
          v.z += bv.z + rf.z;
          v.w += bv.w + rf.w;
        }
        *(float4*)((float*)Cout + grow * N + gcol) = v;
      }
    }
  }
}

__global__ __launch_bounds__(512, 4) void gemm_q_k(const short* A,
                                                   const short* Bt, short* C) {
  gemm256<0, 640>(A, Bt, C, nullptr, nullptr, HID_, blockIdx.x * 256,
                  blockIdx.y * 128);
}

__global__ __launch_bounds__(512, 4) void gemm_out_f32r(const short* A,
                                                        const short* Bt,
                                                        float* C,
                                                        const float* bias,
                                                        const float* resid) {
  gemm256<1, 640>(A, Bt, C, bias, resid, HID_, blockIdx.x * 256,
                  blockIdx.y * 128);
}

__global__ __launch_bounds__(512, 4) void gemm_out_b16r(const short* A,
                                                        const short* Bt,
                                                        float* C,
                                                        const float* bias,
                                                        const short* resid) {
  gemm256<2, 640>(A, Bt, C, bias, resid, HID_, blockIdx.x * 256,
                  blockIdx.y * 128);
}

// proj4 as full gemm256 over padded bf16 A (encb 768 rows / aub 256 rows).
__global__ __launch_bounds__(512, 4) void proj4_k(const short* encb,
                                                  const short* aub,
                                                  const short* Wkt,
                                                  const short* Wvt,
                                                  const short* Waukt,
                                                  const short* Wauvt,
                                                  short* Kb, short* Vb,
                                                  short* AKb, short* AVb) {
  int z = blockIdx.z;
  if (z >= 2 && blockIdx.x > 0) return;
  const short* A = (z < 2) ? encb : aub;
  const short* Bt = (z == 0) ? Wkt : (z == 1) ? Wvt : (z == 2) ? Waukt : Wauvt;
  short* O = (z == 0) ? Kb : (z == 1) ? Vb : (z == 2) ? AKb : AVb;
  gemm256<0, 768>(A, Bt, O, nullptr, nullptr, HID_, blockIdx.x * 256,
                  blockIdx.y * 128);
}

// ---------------------------------------------------------------- attention
// R17 structure (best measured): Qt via gload16 + per-wave vmcnt(0); AU folded
// into PV (AUV -> Vt cols 80..95, g-prescaled mask -> Pl cols 80..95); no-max
// softmax (scores O(5); masked cols exp(-1e30)=+0); LDS 47.5 KB -> 3
// blocks/CU; zero barriers in the q-loop; Ob may alias Qb (race-free).
__global__ __launch_bounds__(256) void attn_k(const short* Qb, const short* Kb,
                                              const short* Vb, const short* AKb,
                                              const short* AVb, short* Ob,
                                              const float* temp,
                                              const float* gate) {
  __shared__ short Qt[64 * 64];   // 8 KB, linear+swizzled (gload16 dest)
  __shared__ short Kl[80][72];    // 11.25 KB (rows 77..79 garbage, masked)
  __shared__ short Vt[64][104];   // 13 KB: V^T kv 0..76 | 0 | AUV^T 80..95
  __shared__ short Pl[64][104];   // 13 KB: P 0..79 | g*mask 80..95
  __shared__ short AUKl[16][72];  // 2.25 KB

  const int t = threadIdx.x;
  const int lane = t & 63, wave = t >> 6;
  const int l15 = lane & 15, lg = lane >> 4;
  const int qbase = blockIdx.x * 512;
  const int h = blockIdx.y;
  const int b = blockIdx.z;
  const int rw = wave * 16;
  f32x4 z4 = {0.f, 0.f, 0.f, 0.f};

  for (int i = t; i < 64 * 3; i += 256) {
    int r = i / 3, c = i - r * 3;
    Vt[r][77 + c] = 0;
  }
#pragma unroll
  for (int j = 0; j < 3; ++j) {
    int i = t + j * 256;
    if (i < KV_ * 8) {
      int r = i >> 3, c8 = i & 7;
      *(int4*)&Kl[r][c8 * 8] =
          *(const int4*)(Kb + (size_t)(b * KV_ + r) * HID_ + h * DH_ + c8 * 8);
    }
  }
  for (int i = t; i < KV_ * DH_; i += 256) {
    int d = i & 63, kv = i >> 6;
    Vt[d][kv] = Vb[(size_t)(b * KV_ + kv) * HID_ + h * DH_ + d];
  }
  if (t < AU_ * 8) {
    int r = t >> 3, c8 = t & 7;
    *(int4*)&AUKl[r][c8 * 8] =
        *(const int4*)(AKb + (size_t)(b * AU_ + r) * HID_ + h * DH_ + c8 * 8);
  }
  for (int i = t; i < AU_ * DH_; i += 256) {
    int d = i & 63, a = i >> 6;
    Vt[d][80 + a] = AVb[(size_t)(b * AU_ + a) * HID_ + h * DH_ + d];
  }
  __syncthreads();  // the ONLY block-wide barrier

  const float invT = 1.f / (fabsf(temp[0]) + 1e-6f);
  const float g = gate[0];  // AU_SCALE = 1

  for (int qi = 0; qi < 8; ++qi) {
    const int q0 = qbase + qi * 64;
#pragma unroll
    for (int i2 = 0; i2 < 2; ++i2) {
      int chunk = wave * 128 + i2 * 64 + lane;
      int r = chunk >> 3, s = chunk & 7;
      const short* src = Qb + (size_t)(b * S_ + q0 + r) * HID_ + h * DH_ +
                         ((s ^ (r & 7)) << 3);
      gload16(src, Qt + (wave * 128 + i2 * 64) * 8);
    }
    asm volatile("s_waitcnt vmcnt(0)" ::: "memory");

    f32x4 accS[5], accA = z4;
#pragma unroll
    for (int c = 0; c < 5; ++c) accS[c] = z4;
#pragma unroll
    for (int ks = 0; ks < 2; ++ks) {
      const char* qrow = (const char*)(Qt + (rw + l15) * 64);
      bf16x8 aq =
          *(const bf16x8*)(qrow + ((ks * 64 + lg * 16) ^ ((l15 & 7) << 4)));
#pragma unroll
      for (int c = 0; c < 5; ++c) {
        bf16x8 bk = *(const bf16x8*)&Kl[c * 16 + l15][ks * 32 + lg * 8];
        accS[c] =
            __builtin_amdgcn_mfma_f32_16x16x32_bf16(aq, bk, accS[c], 0, 0, 0);
      }
      bf16x8 ba = *(const bf16x8*)&AUKl[l15][ks * 32 + lg * 8];
      accA = __builtin_amdgcn_mfma_f32_16x16x32_bf16(aq, ba, accA, 0, 0, 0);
    }

    // softmax WITHOUT max-subtraction (scores O(5); masked -> exp(-1e30)=0)
#pragma unroll
    for (int j = 0; j < 4; ++j) {
      float p[5];
      float s = 0.f;
#pragma unroll
      for (int c = 0; c < 5; ++c) {
        int col = c * 16 + l15;
        float vv = (col < KV_) ? accS[c][j] * SCALE_ : -1e30f;
        p[c] = __expf(vv);
        s += p[c];
      }
#pragma unroll
      for (int off = 1; off < 16; off <<= 1) s += __shfl_xor(s, off);
      float inv = 1.f / s;
      int r = rw + lg * 4 + j;
#pragma unroll
      for (int c = 0; c < 5; ++c) Pl[r][c * 16 + l15] = bfc(p[c] * inv);
      int gi = q0 + r;
      float lx = -1.f + 2.f * (float)(gi & 63) / 63.f;
      float ly = -1.f + 2.f * (float)(gi >> 6 & 63) / 63.f;
      float pr = __expf(-(lx * lx + ly * ly) * (1.0f / 0.605f));
      float as = accA[j] * SCALE_ * invT;
      float sg = 1.f / (1.f + __expf(-as));
      Pl[r][80 + l15] = bfc((sg * pr * 0.9f + 0.1f) * g);
    }
    // no barrier: PV reads only this wave's own Pl rows

    f32x4 accO[4];
#pragma unroll
    for (int c = 0; c < 4; ++c) accO[c] = z4;
#pragma unroll
    for (int kk = 0; kk < 96; kk += 32) {
      bf16x8 ap = *(const bf16x8*)&Pl[rw + l15][kk + lg * 8];
#pragma unroll
      for (int c = 0; c < 4; ++c) {
        bf16x8 bv = *(const bf16x8*)&Vt[c * 16 + l15][kk + lg * 8];
        accO[c] =
            __builtin_amdgcn_mfma_f32_16x16x32_bf16(ap, bv, accO[c], 0, 0, 0);
      }
    }
#pragma unroll
    for (int c = 0; c < 4; ++c)
#pragma unroll
      for (int j = 0; j < 4; ++j) {
        int r = rw + lg * 4 + j;
        Pl[r][c * 16 + l15] = bfc(accO[c][j]);
      }
#pragma unroll
    for (int i2 = 0; i2 < 2; ++i2) {
      int idx = lane + i2 * 64;
      int r = rw + (idx >> 3), cg = idx & 7;
      *(int4*)(Ob + (size_t)(b * S_ + q0 + r) * HID_ + h * DH_ + cg * 8) =
          *(const int4*)&Pl[r][cg * 8];
    }
  }
}

// ---------------------------------------------------------------- launcher
extern "C" void kernel_launch(void* const* d_in, const int* in_sizes, int n_in,
                              void* d_out, int out_size, void* d_ws,
                              size_t ws_size, hipStream_t stream) {
  const float* hs = (const float*)d_in[0];
  const float* enc = (const float*)d_in[1];
  const float* au = (const float*)d_in[2];
  const float* Wq = (const float*)d_in[3];
  const float* Wk = (const float*)d_in[4];
  const float* Wv = (const float*)d_in[5];
  const float* Wauk = (const float*)d_in[6];
  const float* Wauv = (const float*)d_in[7];
  const float* Wout = (const float*)d_in[8];
  const float* bout = (const float*)d_in[9];
  const float* temp = (const float*)d_in[10];
  const float* gate = (const float*)d_in[11];
  float* out = (float*)d_out;
  char* ws = (char*)d_ws;

  const size_t szKpad = (size_t)768 * HID_ * 2;
  const size_t szAUpad = (size_t)256 * HID_ * 2;
  const size_t szW640 = (size_t)HID_ * HID_ * 2;
  const size_t szW768 = (size_t)HID_ * CROSS_ * 2;
  const size_t szENC = (size_t)768 * CROSS_ * 2;
  const size_t szAUB = (size_t)256 * CROSS_ * 2;
  const size_t szHS = (size_t)B_ * S_ * HID_ * 2;

  size_t off = 0;
  short* Kbf = (short*)(ws + off);    off += szKpad;
  short* Vbf = (short*)(ws + off);    off += szKpad;
  short* AUKbf = (short*)(ws + off);  off += szAUpad;
  short* AUVbf = (short*)(ws + off);  off += szAUpad;
  short* Wqt = (short*)(ws + off);    off += szW640;
  short* Wkt = (short*)(ws + off);    off += szW768;
  short* Wvt = (short*)(ws + off);    off += szW768;
  short* Waukt = (short*)(ws + off);  off += szW768;
  short* Wauvt = (short*)(ws + off);  off += szW768;
  short* Woutt = (short*)(ws + off);  off += szW640;
  short* encb = (short*)(ws + off);   off += szENC;
  short* aub = (short*)(ws + off);    off += szAUB;
  short* Qbf = (short*)(ws + off);    off += szHS;
  short* Abf = Qbf;                   // ALIAS: attn overwrites Q in place

  bool hsb_in_ws = (ws_size >= off + szHS);
  short* hsb = hsb_in_ws ? (short*)(ws + off) : (short*)d_out;

  prep_k<<<11344, 256, 0, stream>>>(hs, hsb, enc, encb, au, aub, Wq, Wk, Wv,
                                    Wauk, Wauv, Wout, Wqt, Wkt, Wvt, Waukt,
                                    Wauvt, Woutt);
  proj4_k<<<dim3(3, 5, 4), 512, 0, stream>>>(encb, aub, Wkt, Wvt, Waukt,
                                             Wauvt, Kbf, Vbf, AUKbf, AUVbf);
  gemm_q_k<<<dim3(128, 5), 512, 0, stream>>>(hsb, Wqt, Qbf);
  attn_k<<<dim3(8, HEADS_, B_), 256, 0, stream>>>(Qbf, Kbf, Vbf, AUKbf, AUVbf,
                                                  Abf, temp, gate);
  if (hsb_in_ws) {
    gemm_out_b16r<<<dim3(128, 5), 512, 0, stream>>>(Abf, Woutt, out, bout,
                                                    hsb);
  } else {
    gemm_out_f32r<<<dim3(128, 5), 512, 0, stream>>>(Abf, Woutt, out, bout,
                                                    hs);
  }
}

// Round 21
// 170.743 us; speedup vs baseline: 1.0822x; 1.0214x over previous
//
#include <hip/hip_runtime.h>
#include <hip/hip_bf16.h>

#define B_ 8
#define S_ 4096
#define HID_ 640
#define KV_ 77
#define AU_ 16
#define CROSS_ 768
#define HEADS_ 10
#define DH_ 64
#define SCALE_ 0.125f

using f32x4 = __attribute__((ext_vector_type(4))) float;
using bf16x8 = __attribute__((ext_vector_type(8))) short;

__device__ __forceinline__ short bfc(float f) {
  __hip_bfloat16 h = __float2bfloat16(f);
  return __builtin_bit_cast(short, h);
}

__device__ __forceinline__ float bf2f(short s) {
  unsigned u = ((unsigned)(unsigned short)s) << 16;
  return __uint_as_float(u);
}

__device__ __forceinline__ void gload16(const void* g, void* lds) {
  __builtin_amdgcn_global_load_lds(
      (const __attribute__((address_space(1))) void*)g,
      (__attribute__((address_space(3))) void*)lds, 16, 0, 0);
}

__device__ __forceinline__ void cvt8(const float* src, short* dst) {
  const float4 a = *(const float4*)src;
  const float4 b = *(const float4*)(src + 4);
  bf16x8 v;
  v[0] = bfc(a.x); v[1] = bfc(a.y); v[2] = bfc(a.z); v[3] = bfc(a.w);
  v[4] = bfc(b.x); v[5] = bfc(b.y); v[6] = bfc(b.z); v[7] = bfc(b.w);
  *(bf16x8*)dst = v;
}

// ------------- prep: hs cvt + weight transpose + enc/au cvt (padded bf16)
__global__ __launch_bounds__(256) void prep_k(
    const float* hs, short* hsb, const float* enc, short* encb,
    const float* au, short* aub, const float* Wq, const float* Wk,
    const float* Wv, const float* Wauk, const float* Wauv, const float* Wout,
    short* Wqt, short* Wkt, short* Wvt, short* Waukt, short* Wauvt,
    short* Woutt) {
  __shared__ short Tl[64][72];
  const int t = threadIdx.x;
  int bid = blockIdx.x;
  if (bid < 10240) {
    int i = bid * 256 + t;
    cvt8(hs + (size_t)i * 8, hsb + (size_t)i * 8);
    return;
  }
  if (bid >= 10960) {
    if (bid < 11191) {
      int c = (bid - 10960) * 256 + t;
      cvt8(enc + (size_t)c * 8, encb + (size_t)c * 8);
    } else if (bid < 11248) {
      int j = (bid - 11191) * 256 + t;
      int4 z = {0, 0, 0, 0};
      *(int4*)(encb + (size_t)616 * 768 + (size_t)j * 8) = z;
    } else if (bid < 11296) {
      int c = (bid - 11248) * 256 + t;
      cvt8(au + (size_t)c * 8, aub + (size_t)c * 8);
    } else {
      int j = (bid - 11296) * 256 + t;
      int4 z = {0, 0, 0, 0};
      *(int4*)(aub + (size_t)128 * 768 + (size_t)j * 8) = z;
    }
    return;
  }
  int wb = bid - 10240;
  int z = wb / 120;
  int rem = wb - z * 120;
  int ky = rem / 10, nx = rem - ky * 10;
  const float* W;
  short* Wt;
  int K;
  switch (z) {
    case 0: W = Wq;   Wt = Wqt;   K = 640; break;
    case 1: W = Wk;   Wt = Wkt;   K = 768; break;
    case 2: W = Wv;   Wt = Wvt;   K = 768; break;
    case 3: W = Wauk; Wt = Waukt; K = 768; break;
    case 4: W = Wauv; Wt = Wauvt; K = 768; break;
    default: W = Wout; Wt = Woutt; K = 640; break;
  }
  int kt = ky * 64, nt = nx * 64;
  if (kt >= K) return;
#pragma unroll
  for (int j = 0; j < 16; ++j) {
    int i = t + j * 256;
    int r = i >> 6, c = i & 63;
    Tl[c][r] = bfc(W[(size_t)(kt + r) * 640 + nt + c]);
  }
  __syncthreads();
#pragma unroll
  for (int j = 0; j < 2; ++j) {
    int i = t + j * 256;
    int nl = i >> 3, c = i & 7;
    *(int4*)&Wt[(size_t)(nt + nl) * K + kt + c * 8] = *(int4*)&Tl[nl][c * 8];
  }
}

// ---------------------------------------------- big GEMM (R6 K-loop + R15
// LDS-bounce vectorized epilogue), templated on K (640 or 768).
template <int EPI, int KDIM>
__device__ __forceinline__ void gemm256(const short* Abf, const short* Bt,
                                        void* Cout, const float* bias,
                                        const void* resid, int N, int m0,
                                        int n0) {
  __shared__ short SH[24576];  // 48 KB: Al [256*64] | Bl [128*64]
  short* Al = SH;
  short* Bl = SH + 16384;
  const int t = threadIdx.x;
  const int lane = t & 63;
  const int wave = t >> 6;  // 0..7
  const int l15 = lane & 15, lg = lane >> 4;
  const int wr = (wave >> 1) * 64;
  const int wc = (wave & 1) * 64;

  f32x4 z4 = {0.f, 0.f, 0.f, 0.f};
  f32x4 acc[4][4];
#pragma unroll
  for (int i = 0; i < 4; ++i)
#pragma unroll
    for (int j = 0; j < 4; ++j) acc[i][j] = z4;

  for (int k0 = 0; k0 < KDIM; k0 += 64) {
#pragma unroll
    for (int i = 0; i < 4; ++i) {
      int chunk = wave * 256 + i * 64 + lane;
      int r = chunk >> 3, s = chunk & 7;
      gload16(Abf + (size_t)(m0 + r) * KDIM + k0 + ((s ^ (r & 7)) << 3),
              Al + (size_t)chunk * 8);
    }
#pragma unroll
    for (int i = 0; i < 2; ++i) {
      int chunk = wave * 128 + i * 64 + lane;
      int r = chunk >> 3, s = chunk & 7;
      gload16(Bt + (size_t)(n0 + r) * KDIM + k0 + ((s ^ (r & 7)) << 3),
              Bl + (size_t)chunk * 8);
    }
    __syncthreads();
#pragma unroll
    for (int ks = 0; ks < 2; ++ks) {
      bf16x8 af[4], bfr[4];
#pragma unroll
      for (int mi = 0; mi < 4; ++mi) {
        int row = wr + mi * 16 + l15;
        af[mi] = *(const bf16x8*)((const char*)(Al + row * 64) +
                                  ((ks * 64 + lg * 16) ^ ((row & 7) << 4)));
      }
#pragma unroll
      for (int ni = 0; ni < 4; ++ni) {
        int row = wc + ni * 16 + l15;
        bfr[ni] = *(const bf16x8*)((const char*)(Bl + row * 64) +
                                   ((ks * 64 + lg * 16) ^ ((row & 7) << 4)));
      }
#pragma unroll
      for (int mi = 0; mi < 4; ++mi)
#pragma unroll
        for (int ni = 0; ni < 4; ++ni)
          acc[mi][ni] = __builtin_amdgcn_mfma_f32_16x16x32_bf16(
              af[mi], bfr[ni], acc[mi][ni], 0, 0, 0);
    }
    __syncthreads();
  }

  // ---------------- epilogue (LDS bounce, vectorized global I/O)
  if (EPI == 0) {
    short* Cl = SH;  // bf16 [128][136]
#pragma unroll
    for (int half = 0; half < 2; ++half) {
      __syncthreads();
      if ((wave >> 2) == half) {
        int lwr = wr & 127;
#pragma unroll
        for (int mi = 0; mi < 4; ++mi)
#pragma unroll
          for (int ni = 0; ni < 4; ++ni)
#pragma unroll
            for (int j = 0; j < 4; ++j)
              Cl[(lwr + mi * 16 + lg * 4 + j) * 136 + wc + ni * 16 + l15] =
                  bfc(acc[mi][ni][j]);
      }
      __syncthreads();
#pragma unroll
      for (int p = 0; p < 4; ++p) {
        int idx = t + p * 512;
        int row = idx >> 4, cg = idx & 15;
        *(int4*)((short*)Cout + (size_t)(m0 + half * 128 + row) * N + n0 +
                 cg * 8) = *(const int4*)(Cl + row * 136 + cg * 8);
      }
    }
  } else {
    float* Clf = (float*)SH;  // f32 [64][132]
    float* biasl = (float*)((char*)SH + 40960);
    if (t < 32) *(float4*)(biasl + t * 4) = *(const float4*)(bias + n0 + t * 4);
#pragma unroll
    for (int q = 0; q < 4; ++q) {
      __syncthreads();
      if ((wave >> 1) == q) {
#pragma unroll
        for (int mi = 0; mi < 4; ++mi)
#pragma unroll
          for (int ni = 0; ni < 4; ++ni)
#pragma unroll
            for (int j = 0; j < 4; ++j)
              Clf[(mi * 16 + lg * 4 + j) * 132 + wc + ni * 16 + l15] =
                  acc[mi][ni][j];
      }
      __syncthreads();
#pragma unroll
      for (int p = 0; p < 4; ++p) {
        int idx = t + p * 512;
        int row = idx >> 5, f4 = idx & 31;
        size_t grow = (size_t)(m0 + q * 64 + row);
        int gcol = n0 + f4 * 4;
        float4 v = *(const float4*)(Clf + row * 132 + f4 * 4);
        float4 bv = *(const float4*)(biasl + f4 * 4);
        if (EPI == 2) {
          short4 rs = *(const short4*)((const short*)resid + grow * N + gcol);
          v.x += bv.x + bf2f(rs.x);
          v.y += bv.y + bf2f(rs.y);
          v.z += bv.z + bf2f(rs.z);
          v.w += bv.w + bf2f(rs.w);
        } else {
          float4 rf = *(const float4*)((const float*)resid + grow * N + gcol);
          v.x += bv.x + rf.x;
          v.y += bv.y + rf.y;
          v.z += bv.z + rf.z;
          v.w += bv.w + rf.w;
        }
        *(float4*)((float*)Cout + grow * N + gcol) = v;
      }
    }
  }
}

// -------------------- merged Q-proj + K/V/AU-proj (same deps: prep only).
// 680 blocks @ 48 KB LDS / 512t -> 3 blocks/CU => all co-resident in one
// round; the 40 proj blocks fill gemm_q's idle slots (proj4 becomes ~free).
__global__ __launch_bounds__(512, 4) void gemmq_proj_k(
    const short* hsb, const short* Wqt, short* Qbf, const short* encb,
    const short* aub, const short* Wkt, const short* Wvt, const short* Waukt,
    const short* Wauvt, short* Kb, short* Vb, short* AKb, short* AVb) {
  int bid = blockIdx.x;
  if (bid < 640) {
    int mt = bid & 127, nt = bid >> 7;
    gemm256<0, 640>(hsb, Wqt, Qbf, nullptr, nullptr, HID_, mt * 256,
                    nt * 128);
    return;
  }
  int r = bid - 640;  // 0..39
  int z, x, y;
  if (r < 15) {
    z = 0; x = r / 5; y = r % 5;
  } else if (r < 30) {
    z = 1; r -= 15; x = r / 5; y = r % 5;
  } else if (r < 35) {
    z = 2; x = 0; y = r - 30;
  } else {
    z = 3; x = 0; y = r - 35;
  }
  const short* A = (z < 2) ? encb : aub;
  const short* Bt = (z == 0) ? Wkt : (z == 1) ? Wvt : (z == 2) ? Waukt : Wauvt;
  short* O = (z == 0) ? Kb : (z == 1) ? Vb : (z == 2) ? AKb : AVb;
  gemm256<0, 768>(A, Bt, O, nullptr, nullptr, HID_, x * 256, y * 128);
}

__global__ __launch_bounds__(512, 4) void gemm_out_f32r(const short* A,
                                                        const short* Bt,
                                                        float* C,
                                                        const float* bias,
                                                        const float* resid) {
  gemm256<1, 640>(A, Bt, C, bias, resid, HID_, blockIdx.x * 256,
                  blockIdx.y * 128);
}

__global__ __launch_bounds__(512, 4) void gemm_out_b16r(const short* A,
                                                        const short* Bt,
                                                        float* C,
                                                        const float* bias,
                                                        const short* resid) {
  gemm256<2, 640>(A, Bt, C, bias, resid, HID_, blockIdx.x * 256,
                  blockIdx.y * 128);
}

// ---------------------------------------------------------------- attention
// R17 structure (best measured): Qt via gload16 + per-wave vmcnt(0); AU folded
// into PV (AUV -> Vt cols 80..95, g-prescaled mask -> Pl cols 80..95); no-max
// softmax (scores O(5); masked cols exp(-1e30)=+0); LDS 47.5 KB -> 3
// blocks/CU; zero barriers in the q-loop; Ob may alias Qb (race-free).
__global__ __launch_bounds__(256) void attn_k(const short* Qb, const short* Kb,
                                              const short* Vb, const short* AKb,
                                              const short* AVb, short* Ob,
                                              const float* temp,
                                              const float* gate) {
  __shared__ short Qt[64 * 64];   // 8 KB, linear+swizzled (gload16 dest)
  __shared__ short Kl[80][72];    // 11.25 KB (rows 77..79 garbage, masked)
  __shared__ short Vt[64][104];   // 13 KB: V^T kv 0..76 | 0 | AUV^T 80..95
  __shared__ short Pl[64][104];   // 13 KB: P 0..79 | g*mask 80..95
  __shared__ short AUKl[16][72];  // 2.25 KB

  const int t = threadIdx.x;
  const int lane = t & 63, wave = t >> 6;
  const int l15 = lane & 15, lg = lane >> 4;
  const int qbase = blockIdx.x * 512;
  const int h = blockIdx.y;
  const int b = blockIdx.z;
  const int rw = wave * 16;
  f32x4 z4 = {0.f, 0.f, 0.f, 0.f};

  for (int i = t; i < 64 * 3; i += 256) {
    int r = i / 3, c = i - r * 3;
    Vt[r][77 + c] = 0;
  }
#pragma unroll
  for (int j = 0; j < 3; ++j) {
    int i = t + j * 256;
    if (i < KV_ * 8) {
      int r = i >> 3, c8 = i & 7;
      *(int4*)&Kl[r][c8 * 8] =
          *(const int4*)(Kb + (size_t)(b * KV_ + r) * HID_ + h * DH_ + c8 * 8);
    }
  }
  for (int i = t; i < KV_ * DH_; i += 256) {
    int d = i & 63, kv = i >> 6;
    Vt[d][kv] = Vb[(size_t)(b * KV_ + kv) * HID_ + h * DH_ + d];
  }
  if (t < AU_ * 8) {
    int r = t >> 3, c8 = t & 7;
    *(int4*)&AUKl[r][c8 * 8] =
        *(const int4*)(AKb + (size_t)(b * AU_ + r) * HID_ + h * DH_ + c8 * 8);
  }
  for (int i = t; i < AU_ * DH_; i += 256) {
    int d = i & 63, a = i >> 6;
    Vt[d][80 + a] = AVb[(size_t)(b * AU_ + a) * HID_ + h * DH_ + d];
  }
  __syncthreads();  // the ONLY block-wide barrier

  const float invT = 1.f / (fabsf(temp[0]) + 1e-6f);
  const float g = gate[0];  // AU_SCALE = 1

  for (int qi = 0; qi < 8; ++qi) {
    const int q0 = qbase + qi * 64;
#pragma unroll
    for (int i2 = 0; i2 < 2; ++i2) {
      int chunk = wave * 128 + i2 * 64 + lane;
      int r = chunk >> 3, s = chunk & 7;
      const short* src = Qb + (size_t)(b * S_ + q0 + r) * HID_ + h * DH_ +
                         ((s ^ (r & 7)) << 3);
      gload16(src, Qt + (wave * 128 + i2 * 64) * 8);
    }
    asm volatile("s_waitcnt vmcnt(0)" ::: "memory");

    f32x4 accS[5], accA = z4;
#pragma unroll
    for (int c = 0; c < 5; ++c) accS[c] = z4;
#pragma unroll
    for (int ks = 0; ks < 2; ++ks) {
      const char* qrow = (const char*)(Qt + (rw + l15) * 64);
      bf16x8 aq =
          *(const bf16x8*)(qrow + ((ks * 64 + lg * 16) ^ ((l15 & 7) << 4)));
#pragma unroll
      for (int c = 0; c < 5; ++c) {
        bf16x8 bk = *(const bf16x8*)&Kl[c * 16 + l15][ks * 32 + lg * 8];
        accS[c] =
            __builtin_amdgcn_mfma_f32_16x16x32_bf16(aq, bk, accS[c], 0, 0, 0);
      }
      bf16x8 ba = *(const bf16x8*)&AUKl[l15][ks * 32 + lg * 8];
      accA = __builtin_amdgcn_mfma_f32_16x16x32_bf16(aq, ba, accA, 0, 0, 0);
    }

    // softmax WITHOUT max-subtraction (scores O(5); masked -> exp(-1e30)=0)
#pragma unroll
    for (int j = 0; j < 4; ++j) {
      float p[5];
      float s = 0.f;
#pragma unroll
      for (int c = 0; c < 5; ++c) {
        int col = c * 16 + l15;
        float vv = (col < KV_) ? accS[c][j] * SCALE_ : -1e30f;
        p[c] = __expf(vv);
        s += p[c];
      }
#pragma unroll
      for (int off = 1; off < 16; off <<= 1) s += __shfl_xor(s, off);
      float inv = 1.f / s;
      int r = rw + lg * 4 + j;
#pragma unroll
      for (int c = 0; c < 5; ++c) Pl[r][c * 16 + l15] = bfc(p[c] * inv);
      int gi = q0 + r;
      float lx = -1.f + 2.f * (float)(gi & 63) / 63.f;
      float ly = -1.f + 2.f * (float)(gi >> 6 & 63) / 63.f;
      float pr = __expf(-(lx * lx + ly * ly) * (1.0f / 0.605f));
      float as = accA[j] * SCALE_ * invT;
      float sg = 1.f / (1.f + __expf(-as));
      Pl[r][80 + l15] = bfc((sg * pr * 0.9f + 0.1f) * g);
    }
    // no barrier: PV reads only this wave's own Pl rows

    f32x4 accO[4];
#pragma unroll
    for (int c = 0; c < 4; ++c) accO[c] = z4;
#pragma unroll
    for (int kk = 0; kk < 96; kk += 32) {
      bf16x8 ap = *(const bf16x8*)&Pl[rw + l15][kk + lg * 8];
#pragma unroll
      for (int c = 0; c < 4; ++c) {
        bf16x8 bv = *(const bf16x8*)&Vt[c * 16 + l15][kk + lg * 8];
        accO[c] =
            __builtin_amdgcn_mfma_f32_16x16x32_bf16(ap, bv, accO[c], 0, 0, 0);
      }
    }
#pragma unroll
    for (int c = 0; c < 4; ++c)
#pragma unroll
      for (int j = 0; j < 4; ++j) {
        int r = rw + lg * 4 + j;
        Pl[r][c * 16 + l15] = bfc(accO[c][j]);
      }
#pragma unroll
    for (int i2 = 0; i2 < 2; ++i2) {
      int idx = lane + i2 * 64;
      int r = rw + (idx >> 3), cg = idx & 7;
      *(int4*)(Ob + (size_t)(b * S_ + q0 + r) * HID_ + h * DH_ + cg * 8) =
          *(const int4*)&Pl[r][cg * 8];
    }
  }
}

// ---------------------------------------------------------------- launcher
extern "C" void kernel_launch(void* const* d_in, const int* in_sizes, int n_in,
                              void* d_out, int out_size, void* d_ws,
                              size_t ws_size, hipStream_t stream) {
  const float* hs = (const float*)d_in[0];
  const float* enc = (const float*)d_in[1];
  const float* au = (const float*)d_in[2];
  const float* Wq = (const float*)d_in[3];
  const float* Wk = (const float*)d_in[4];
  const float* Wv = (const float*)d_in[5];
  const float* Wauk = (const float*)d_in[6];
  const float* Wauv = (const float*)d_in[7];
  const float* Wout = (const float*)d_in[8];
  const float* bout = (const float*)d_in[9];
  const float* temp = (const float*)d_in[10];
  const float* gate = (const float*)d_in[11];
  float* out = (float*)d_out;
  char* ws = (char*)d_ws;

  const size_t szKpad = (size_t)768 * HID_ * 2;
  const size_t szAUpad = (size_t)256 * HID_ * 2;
  const size_t szW640 = (size_t)HID_ * HID_ * 2;
  const size_t szW768 = (size_t)HID_ * CROSS_ * 2;
  const size_t szENC = (size_t)768 * CROSS_ * 2;
  const size_t szAUB = (size_t)256 * CROSS_ * 2;
  const size_t szHS = (size_t)B_ * S_ * HID_ * 2;

  size_t off = 0;
  short* Kbf = (short*)(ws + off);    off += szKpad;
  short* Vbf = (short*)(ws + off);    off += szKpad;
  short* AUKbf = (short*)(ws + off);  off += szAUpad;
  short* AUVbf = (short*)(ws + off);  off += szAUpad;
  short* Wqt = (short*)(ws + off);    off += szW640;
  short* Wkt = (short*)(ws + off);    off += szW768;
  short* Wvt = (short*)(ws + off);    off += szW768;
  short* Waukt = (short*)(ws + off);  off += szW768;
  short* Wauvt = (short*)(ws + off);  off += szW768;
  short* Woutt = (short*)(ws + off);  off += szW640;
  short* encb = (short*)(ws + off);   off += szENC;
  short* aub = (short*)(ws + off);    off += szAUB;
  short* Qbf = (short*)(ws + off);    off += szHS;
  short* Abf = Qbf;                   // ALIAS: attn overwrites Q in place

  bool hsb_in_ws = (ws_size >= off + szHS);
  short* hsb = hsb_in_ws ? (short*)(ws + off) : (short*)d_out;

  prep_k<<<11344, 256, 0, stream>>>(hs, hsb, enc, encb, au, aub, Wq, Wk, Wv,
                                    Wauk, Wauv, Wout, Wqt, Wkt, Wvt, Waukt,
                                    Wauvt, Woutt);
  gemmq_proj_k<<<680, 512, 0, stream>>>(hsb, Wqt, Qbf, encb, aub, Wkt, Wvt,
                                        Waukt, Wauvt, Kbf, Vbf, AUKbf, AUVbf);
  attn_k<<<dim3(8, HEADS_, B_), 256, 0, stream>>>(Qbf, Kbf, Vbf, AUKbf, AUVbf,
                                                  Abf, temp, gate);
  if (hsb_in_ws) {
    gemm_out_b16r<<<dim3(128, 5), 512, 0, stream>>>(Abf, Woutt, out, bout,
                                                    hsb);
  } else {
    gemm_out_f32r<<<dim3(128, 5), 512, 0, stream>>>(Abf, Woutt, out, bout,
                                                    hs);
  }
}

// Round 22
// 159.634 us; speedup vs baseline: 1.1575x; 1.0696x over previous
//
#include <hip/hip_runtime.h>
#include <hip/hip_bf16.h>

#define B_ 8
#define S_ 4096
#define HID_ 640
#define KV_ 77
#define AU_ 16
#define CROSS_ 768
#define HEADS_ 10
#define DH_ 64
#define SCALE_ 0.125f

using f32x4 = __attribute__((ext_vector_type(4))) float;
using bf16x8 = __attribute__((ext_vector_type(8))) short;

__device__ __forceinline__ short bfc(float f) {
  __hip_bfloat16 h = __float2bfloat16(f);
  return __builtin_bit_cast(short, h);
}

__device__ __forceinline__ float bf2f(short s) {
  unsigned u = ((unsigned)(unsigned short)s) << 16;
  return __uint_as_float(u);
}

__device__ __forceinline__ void gload16(const void* g, void* lds) {
  __builtin_amdgcn_global_load_lds(
      (const __attribute__((address_space(1))) void*)g,
      (__attribute__((address_space(3))) void*)lds, 16, 0, 0);
}

__device__ __forceinline__ void cvt8(const float* src, short* dst) {
  const float4 a = *(const float4*)src;
  const float4 b = *(const float4*)(src + 4);
  bf16x8 v;
  v[0] = bfc(a.x); v[1] = bfc(a.y); v[2] = bfc(a.z); v[3] = bfc(a.w);
  v[4] = bfc(b.x); v[5] = bfc(b.y); v[6] = bfc(b.z); v[7] = bfc(b.w);
  *(bf16x8*)dst = v;
}

// ------------- prep: hs cvt + weight transpose + enc/au cvt (padded bf16)
__global__ __launch_bounds__(256) void prep_k(
    const float* hs, short* hsb, const float* enc, short* encb,
    const float* au, short* aub, const float* Wq, const float* Wk,
    const float* Wv, const float* Wauk, const float* Wauv, const float* Wout,
    short* Wqt, short* Wkt, short* Wvt, short* Waukt, short* Wauvt,
    short* Woutt) {
  __shared__ short Tl[64][72];
  const int t = threadIdx.x;
  int bid = blockIdx.x;
  if (bid < 10240) {
    int i = bid * 256 + t;
    cvt8(hs + (size_t)i * 8, hsb + (size_t)i * 8);
    return;
  }
  if (bid >= 10960) {
    if (bid < 11191) {
      int c = (bid - 10960) * 256 + t;
      cvt8(enc + (size_t)c * 8, encb + (size_t)c * 8);
    } else if (bid < 11248) {
      int j = (bid - 11191) * 256 + t;
      int4 z = {0, 0, 0, 0};
      *(int4*)(encb + (size_t)616 * 768 + (size_t)j * 8) = z;
    } else if (bid < 11296) {
      int c = (bid - 11248) * 256 + t;
      cvt8(au + (size_t)c * 8, aub + (size_t)c * 8);
    } else {
      int j = (bid - 11296) * 256 + t;
      int4 z = {0, 0, 0, 0};
      *(int4*)(aub + (size_t)128 * 768 + (size_t)j * 8) = z;
    }
    return;
  }
  int wb = bid - 10240;
  int z = wb / 120;
  int rem = wb - z * 120;
  int ky = rem / 10, nx = rem - ky * 10;
  const float* W;
  short* Wt;
  int K;
  switch (z) {
    case 0: W = Wq;   Wt = Wqt;   K = 640; break;
    case 1: W = Wk;   Wt = Wkt;   K = 768; break;
    case 2: W = Wv;   Wt = Wvt;   K = 768; break;
    case 3: W = Wauk; Wt = Waukt; K = 768; break;
    case 4: W = Wauv; Wt = Wauvt; K = 768; break;
    default: W = Wout; Wt = Woutt; K = 640; break;
  }
  int kt = ky * 64, nt = nx * 64;
  if (kt >= K) return;
#pragma unroll
  for (int j = 0; j < 16; ++j) {
    int i = t + j * 256;
    int r = i >> 6, c = i & 63;
    Tl[c][r] = bfc(W[(size_t)(kt + r) * 640 + nt + c]);
  }
  __syncthreads();
#pragma unroll
  for (int j = 0; j < 2; ++j) {
    int i = t + j * 256;
    int nl = i >> 3, c = i & 7;
    *(int4*)&Wt[(size_t)(nt + nl) * K + kt + c * 8] = *(int4*)&Tl[nl][c * 8];
  }
}

// ---------------------------------------------- big GEMM (R6 K-loop + R15
// LDS-bounce vectorized epilogue), templated on K (640 or 768).
// SH: caller-provided 48 KB LDS (shared across template instantiations so a
// kernel with two instantiations still allocates only 48 KB).
template <int EPI, int KDIM>
__device__ __forceinline__ void gemm256(short* SH, const short* Abf,
                                        const short* Bt, void* Cout,
                                        const float* bias, const void* resid,
                                        int N, int m0, int n0) {
  short* Al = SH;
  short* Bl = SH + 16384;
  const int t = threadIdx.x;
  const int lane = t & 63;
  const int wave = t >> 6;  // 0..7
  const int l15 = lane & 15, lg = lane >> 4;
  const int wr = (wave >> 1) * 64;
  const int wc = (wave & 1) * 64;

  f32x4 z4 = {0.f, 0.f, 0.f, 0.f};
  f32x4 acc[4][4];
#pragma unroll
  for (int i = 0; i < 4; ++i)
#pragma unroll
    for (int j = 0; j < 4; ++j) acc[i][j] = z4;

  for (int k0 = 0; k0 < KDIM; k0 += 64) {
#pragma unroll
    for (int i = 0; i < 4; ++i) {
      int chunk = wave * 256 + i * 64 + lane;
      int r = chunk >> 3, s = chunk & 7;
      gload16(Abf + (size_t)(m0 + r) * KDIM + k0 + ((s ^ (r & 7)) << 3),
              Al + (size_t)chunk * 8);
    }
#pragma unroll
    for (int i = 0; i < 2; ++i) {
      int chunk = wave * 128 + i * 64 + lane;
      int r = chunk >> 3, s = chunk & 7;
      gload16(Bt + (size_t)(n0 + r) * KDIM + k0 + ((s ^ (r & 7)) << 3),
              Bl + (size_t)chunk * 8);
    }
    __syncthreads();
#pragma unroll
    for (int ks = 0; ks < 2; ++ks) {
      bf16x8 af[4], bfr[4];
#pragma unroll
      for (int mi = 0; mi < 4; ++mi) {
        int row = wr + mi * 16 + l15;
        af[mi] = *(const bf16x8*)((const char*)(Al + row * 64) +
                                  ((ks * 64 + lg * 16) ^ ((row & 7) << 4)));
      }
#pragma unroll
      for (int ni = 0; ni < 4; ++ni) {
        int row = wc + ni * 16 + l15;
        bfr[ni] = *(const bf16x8*)((const char*)(Bl + row * 64) +
                                   ((ks * 64 + lg * 16) ^ ((row & 7) << 4)));
      }
#pragma unroll
      for (int mi = 0; mi < 4; ++mi)
#pragma unroll
        for (int ni = 0; ni < 4; ++ni)
          acc[mi][ni] = __builtin_amdgcn_mfma_f32_16x16x32_bf16(
              af[mi], bfr[ni], acc[mi][ni], 0, 0, 0);
    }
    __syncthreads();
  }

  // ---------------- epilogue (LDS bounce, vectorized global I/O)
  if (EPI == 0) {
    short* Cl = SH;  // bf16 [128][136]
#pragma unroll
    for (int half = 0; half < 2; ++half) {
      __syncthreads();
      if ((wave >> 2) == half) {
        int lwr = wr & 127;
#pragma unroll
        for (int mi = 0; mi < 4; ++mi)
#pragma unroll
          for (int ni = 0; ni < 4; ++ni)
#pragma unroll
            for (int j = 0; j < 4; ++j)
              Cl[(lwr + mi * 16 + lg * 4 + j) * 136 + wc + ni * 16 + l15] =
                  bfc(acc[mi][ni][j]);
      }
      __syncthreads();
#pragma unroll
      for (int p = 0; p < 4; ++p) {
        int idx = t + p * 512;
        int row = idx >> 4, cg = idx & 15;
        *(int4*)((short*)Cout + (size_t)(m0 + half * 128 + row) * N + n0 +
                 cg * 8) = *(const int4*)(Cl + row * 136 + cg * 8);
      }
    }
  } else {
    float* Clf = (float*)SH;  // f32 [64][132]
    float* biasl = (float*)((char*)SH + 40960);
    if (t < 32) *(float4*)(biasl + t * 4) = *(const float4*)(bias + n0 + t * 4);
#pragma unroll
    for (int q = 0; q < 4; ++q) {
      __syncthreads();
      if ((wave >> 1) == q) {
#pragma unroll
        for (int mi = 0; mi < 4; ++mi)
#pragma unroll
          for (int ni = 0; ni < 4; ++ni)
#pragma unroll
            for (int j = 0; j < 4; ++j)
              Clf[(mi * 16 + lg * 4 + j) * 132 + wc + ni * 16 + l15] =
                  acc[mi][ni][j];
      }
      __syncthreads();
#pragma unroll
      for (int p = 0; p < 4; ++p) {
        int idx = t + p * 512;
        int row = idx >> 5, f4 = idx & 31;
        size_t grow = (size_t)(m0 + q * 64 + row);
        int gcol = n0 + f4 * 4;
        float4 v = *(const float4*)(Clf + row * 132 + f4 * 4);
        float4 bv = *(const float4*)(biasl + f4 * 4);
        if (EPI == 2) {
          short4 rs = *(const short4*)((const short*)resid + grow * N + gcol);
          v.x += bv.x + bf2f(rs.x);
          v.y += bv.y + bf2f(rs.y);
          v.z += bv.z + bf2f(rs.z);
          v.w += bv.w + bf2f(rs.w);
        } else {
          float4 rf = *(const float4*)((const float*)resid + grow * N + gcol);
          v.x += bv.x + rf.x;
          v.y += bv.y + rf.y;
          v.z += bv.z + rf.z;
          v.w += bv.w + rf.w;
        }
        *(float4*)((float*)Cout + grow * N + gcol) = v;
      }
    }
  }
}

// -------------------- merged Q-proj + K/V/AU-proj (same deps: prep only).
// ONE shared 48 KB buffer for both instantiations -> 3 blocks/CU; 680 blocks
// all co-resident in one round (the 40 proj blocks fill gemm_q's idle slots).
__global__ __launch_bounds__(512, 4) void gemmq_proj_k(
    const short* hsb, const short* Wqt, short* Qbf, const short* encb,
    const short* aub, const short* Wkt, const short* Wvt, const short* Waukt,
    const short* Wauvt, short* Kb, short* Vb, short* AKb, short* AVb) {
  __shared__ short SH[24576];
  int bid = blockIdx.x;
  if (bid < 640) {
    int mt = bid & 127, nt = bid >> 7;
    gemm256<0, 640>(SH, hsb, Wqt, Qbf, nullptr, nullptr, HID_, mt * 256,
                    nt * 128);
    return;
  }
  int r = bid - 640;  // 0..39
  int z, x, y;
  if (r < 15) {
    z = 0; x = r / 5; y = r % 5;
  } else if (r < 30) {
    z = 1; r -= 15; x = r / 5; y = r % 5;
  } else if (r < 35) {
    z = 2; x = 0; y = r - 30;
  } else {
    z = 3; x = 0; y = r - 35;
  }
  const short* A = (z < 2) ? encb : aub;
  const short* Bt = (z == 0) ? Wkt : (z == 1) ? Wvt : (z == 2) ? Waukt : Wauvt;
  short* O = (z == 0) ? Kb : (z == 1) ? Vb : (z == 2) ? AKb : AVb;
  gemm256<0, 768>(SH, A, Bt, O, nullptr, nullptr, HID_, x * 256, y * 128);
}

__global__ __launch_bounds__(512, 4) void gemm_out_f32r(const short* A,
                                                        const short* Bt,
                                                        float* C,
                                                        const float* bias,
                                                        const float* resid) {
  __shared__ short SH[24576];
  gemm256<1, 640>(SH, A, Bt, C, bias, resid, HID_, blockIdx.x * 256,
                  blockIdx.y * 128);
}

__global__ __launch_bounds__(512, 4) void gemm_out_b16r(const short* A,
                                                        const short* Bt,
                                                        float* C,
                                                        const float* bias,
                                                        const short* resid) {
  __shared__ short SH[24576];
  gemm256<2, 640>(SH, A, Bt, C, bias, resid, HID_, blockIdx.x * 256,
                  blockIdx.y * 128);
}

// ---------------------------------------------------------------- attention
// R17 structure (best measured): Qt via gload16 + per-wave vmcnt(0); AU folded
// into PV (AUV -> Vt cols 80..95, g-prescaled mask -> Pl cols 80..95); no-max
// softmax (scores O(5); masked cols exp(-1e30)=+0); LDS 47.5 KB -> 3
// blocks/CU; zero barriers in the q-loop; Ob may alias Qb (race-free).
__global__ __launch_bounds__(256) void attn_k(const short* Qb, const short* Kb,
                                              const short* Vb, const short* AKb,
                                              const short* AVb, short* Ob,
                                              const float* temp,
                                              const float* gate) {
  __shared__ short Qt[64 * 64];   // 8 KB, linear+swizzled (gload16 dest)
  __shared__ short Kl[80][72];    // 11.25 KB (rows 77..79 garbage, masked)
  __shared__ short Vt[64][104];   // 13 KB: V^T kv 0..76 | 0 | AUV^T 80..95
  __shared__ short Pl[64][104];   // 13 KB: P 0..79 | g*mask 80..95
  __shared__ short AUKl[16][72];  // 2.25 KB

  const int t = threadIdx.x;
  const int lane = t & 63, wave = t >> 6;
  const int l15 = lane & 15, lg = lane >> 4;
  const int qbase = blockIdx.x * 512;
  const int h = blockIdx.y;
  const int b = blockIdx.z;
  const int rw = wave * 16;
  f32x4 z4 = {0.f, 0.f, 0.f, 0.f};

  for (int i = t; i < 64 * 3; i += 256) {
    int r = i / 3, c = i - r * 3;
    Vt[r][77 + c] = 0;
  }
#pragma unroll
  for (int j = 0; j < 3; ++j) {
    int i = t + j * 256;
    if (i < KV_ * 8) {
      int r = i >> 3, c8 = i & 7;
      *(int4*)&Kl[r][c8 * 8] =
          *(const int4*)(Kb + (size_t)(b * KV_ + r) * HID_ + h * DH_ + c8 * 8);
    }
  }
  for (int i = t; i < KV_ * DH_; i += 256) {
    int d = i & 63, kv = i >> 6;
    Vt[d][kv] = Vb[(size_t)(b * KV_ + kv) * HID_ + h * DH_ + d];
  }
  if (t < AU_ * 8) {
    int r = t >> 3, c8 = t & 7;
    *(int4*)&AUKl[r][c8 * 8] =
        *(const int4*)(AKb + (size_t)(b * AU_ + r) * HID_ + h * DH_ + c8 * 8);
  }
  for (int i = t; i < AU_ * DH_; i += 256) {
    int d = i & 63, a = i >> 6;
    Vt[d][80 + a] = AVb[(size_t)(b * AU_ + a) * HID_ + h * DH_ + d];
  }
  __syncthreads();  // the ONLY block-wide barrier

  const float invT = 1.f / (fabsf(temp[0]) + 1e-6f);
  const float g = gate[0];  // AU_SCALE = 1

  for (int qi = 0; qi < 8; ++qi) {
    const int q0 = qbase + qi * 64;
#pragma unroll
    for (int i2 = 0; i2 < 2; ++i2) {
      int chunk = wave * 128 + i2 * 64 + lane;
      int r = chunk >> 3, s = chunk & 7;
      const short* src = Qb + (size_t)(b * S_ + q0 + r) * HID_ + h * DH_ +
                         ((s ^ (r & 7)) << 3);
      gload16(src, Qt + (wave * 128 + i2 * 64) * 8);
    }
    asm volatile("s_waitcnt vmcnt(0)" ::: "memory");

    f32x4 accS[5], accA = z4;
#pragma unroll
    for (int c = 0; c < 5; ++c) accS[c] = z4;
#pragma unroll
    for (int ks = 0; ks < 2; ++ks) {
      const char* qrow = (const char*)(Qt + (rw + l15) * 64);
      bf16x8 aq =
          *(const bf16x8*)(qrow + ((ks * 64 + lg * 16) ^ ((l15 & 7) << 4)));
#pragma unroll
      for (int c = 0; c < 5; ++c) {
        bf16x8 bk = *(const bf16x8*)&Kl[c * 16 + l15][ks * 32 + lg * 8];
        accS[c] =
            __builtin_amdgcn_mfma_f32_16x16x32_bf16(aq, bk, accS[c], 0, 0, 0);
      }
      bf16x8 ba = *(const bf16x8*)&AUKl[l15][ks * 32 + lg * 8];
      accA = __builtin_amdgcn_mfma_f32_16x16x32_bf16(aq, ba, accA, 0, 0, 0);
    }

    // softmax WITHOUT max-subtraction (scores O(5); masked -> exp(-1e30)=0)
#pragma unroll
    for (int j = 0; j < 4; ++j) {
      float p[5];
      float s = 0.f;
#pragma unroll
      for (int c = 0; c < 5; ++c) {
        int col = c * 16 + l15;
        float vv = (col < KV_) ? accS[c][j] * SCALE_ : -1e30f;
        p[c] = __expf(vv);
        s += p[c];
      }
#pragma unroll
      for (int off = 1; off < 16; off <<= 1) s += __shfl_xor(s, off);
      float inv = 1.f / s;
      int r = rw + lg * 4 + j;
#pragma unroll
      for (int c = 0; c < 5; ++c) Pl[r][c * 16 + l15] = bfc(p[c] * inv);
      int gi = q0 + r;
      float lx = -1.f + 2.f * (float)(gi & 63) / 63.f;
      float ly = -1.f + 2.f * (float)(gi >> 6 & 63) / 63.f;
      float pr = __expf(-(lx * lx + ly * ly) * (1.0f / 0.605f));
      float as = accA[j] * SCALE_ * invT;
      float sg = 1.f / (1.f + __expf(-as));
      Pl[r][80 + l15] = bfc((sg * pr * 0.9f + 0.1f) * g);
    }
    // no barrier: PV reads only this wave's own Pl rows

    f32x4 accO[4];
#pragma unroll
    for (int c = 0; c < 4; ++c) accO[c] = z4;
#pragma unroll
    for (int kk = 0; kk < 96; kk += 32) {
      bf16x8 ap = *(const bf16x8*)&Pl[rw + l15][kk + lg * 8];
#pragma unroll
      for (int c = 0; c < 4; ++c) {
        bf16x8 bv = *(const bf16x8*)&Vt[c * 16 + l15][kk + lg * 8];
        accO[c] =
            __builtin_amdgcn_mfma_f32_16x16x32_bf16(ap, bv, accO[c], 0, 0, 0);
      }
    }
#pragma unroll
    for (int c = 0; c < 4; ++c)
#pragma unroll
      for (int j = 0; j < 4; ++j) {
        int r = rw + lg * 4 + j;
        Pl[r][c * 16 + l15] = bfc(accO[c][j]);
      }
#pragma unroll
    for (int i2 = 0; i2 < 2; ++i2) {
      int idx = lane + i2 * 64;
      int r = rw + (idx >> 3), cg = idx & 7;
      *(int4*)(Ob + (size_t)(b * S_ + q0 + r) * HID_ + h * DH_ + cg * 8) =
          *(const int4*)&Pl[r][cg * 8];
    }
  }
}

// ---------------------------------------------------------------- launcher
extern "C" void kernel_launch(void* const* d_in, const int* in_sizes, int n_in,
                              void* d_out, int out_size, void* d_ws,
                              size_t ws_size, hipStream_t stream) {
  const float* hs = (const float*)d_in[0];
  const float* enc = (const float*)d_in[1];
  const float* au = (const float*)d_in[2];
  const float* Wq = (const float*)d_in[3];
  const float* Wk = (const float*)d_in[4];
  const float* Wv = (const float*)d_in[5];
  const float* Wauk = (const float*)d_in[6];
  const float* Wauv = (const float*)d_in[7];
  const float* Wout = (const float*)d_in[8];
  const float* bout = (const float*)d_in[9];
  const float* temp = (const float*)d_in[10];
  const float* gate = (const float*)d_in[11];
  float* out = (float*)d_out;
  char* ws = (char*)d_ws;

  const size_t szKpad = (size_t)768 * HID_ * 2;
  const size_t szAUpad = (size_t)256 * HID_ * 2;
  const size_t szW640 = (size_t)HID_ * HID_ * 2;
  const size_t szW768 = (size_t)HID_ * CROSS_ * 2;
  const size_t szENC = (size_t)768 * CROSS_ * 2;
  const size_t szAUB = (size_t)256 * CROSS_ * 2;
  const size_t szHS = (size_t)B_ * S_ * HID_ * 2;

  size_t off = 0;
  short* Kbf = (short*)(ws + off);    off += szKpad;
  short* Vbf = (short*)(ws + off);    off += szKpad;
  short* AUKbf = (short*)(ws + off);  off += szAUpad;
  short* AUVbf = (short*)(ws + off);  off += szAUpad;
  short* Wqt = (short*)(ws + off);    off += szW640;
  short* Wkt = (short*)(ws + off);    off += szW768;
  short* Wvt = (short*)(ws + off);    off += szW768;
  short* Waukt = (short*)(ws + off);  off += szW768;
  short* Wauvt = (short*)(ws + off);  off += szW768;
  short* Woutt = (short*)(ws + off);  off += szW640;
  short* encb = (short*)(ws + off);   off += szENC;
  short* aub = (short*)(ws + off);    off += szAUB;
  short* Qbf = (short*)(ws + off);    off += szHS;
  short* Abf = Qbf;                   // ALIAS: attn overwrites Q in place

  bool hsb_in_ws = (ws_size >= off + szHS);
  short* hsb = hsb_in_ws ? (short*)(ws + off) : (short*)d_out;

  prep_k<<<11344, 256, 0, stream>>>(hs, hsb, enc, encb, au, aub, Wq, Wk, Wv,
                                    Wauk, Wauv, Wout, Wqt, Wkt, Wvt, Waukt,
                                    Wauvt, Woutt);
  gemmq_proj_k<<<680, 512, 0, stream>>>(hsb, Wqt, Qbf, encb, aub, Wkt, Wvt,
                                        Waukt, Wauvt, Kbf, Vbf, AUKbf, AUVbf);
  attn_k<<<dim3(8, HEADS_, B_), 256, 0, stream>>>(Qbf, Kbf, Vbf, AUKbf, AUVbf,
                                                  Abf, temp, gate);
  if (hsb_in_ws) {
    gemm_out_b16r<<<dim3(128, 5), 512, 0, stream>>>(Abf, Woutt, out, bout,
                                                    hsb);
  } else {
    gemm_out_f32r<<<dim3(128, 5), 512, 0, stream>>>(Abf, Woutt, out, bout,
                                                    hs);
  }
}